// Round 2
// baseline (817.755 us; speedup 1.0000x reference)
//
#include <hip/hip_runtime.h>
#include <hip/hip_bf16.h>

#define Bb 64
#define Ll 200
#define NSs 1000
#define Dd 128
#define Mm 50

// ---------------- kernel 1: attention weights w = softmax(k @ Mk^T) ----------------
// grid = B*L blocks, 64 threads (1 wave). Lane m<50 computes one logit.
__global__ void kern_w(const int* __restrict__ skills,
                       const float* __restrict__ k_emb,
                       const float* __restrict__ Mk,
                       float* __restrict__ w_out) {
    int bl = blockIdx.x;
    int t  = threadIdx.x;
    __shared__ float krow[Dd];
    int sk = skills[bl];
    for (int d = t; d < Dd; d += 64) krow[d] = k_emb[sk * Dd + d];
    __syncthreads();
    float logit = -1e30f;
    if (t < Mm) {
        float acc = 0.f;
        const float* mk = Mk + t * Dd;
#pragma unroll 4
        for (int d = 0; d < Dd; ++d) acc = fmaf(krow[d], mk[d], acc);
        logit = acc;
    }
    float mx = logit;
    for (int off = 32; off > 0; off >>= 1) mx = fmaxf(mx, __shfl_down(mx, off));
    mx = __shfl(mx, 0);
    float ex = (t < Mm) ? expf(logit - mx) : 0.f;
    float sm = ex;
    for (int off = 32; off > 0; off >>= 1) sm += __shfl_down(sm, off);
    sm = __shfl(sm, 0);
    if (t < Mm) w_out[bl * Mm + t] = ex / sm;
}

// ---------------- kernel 2: e = sigmoid(v@eW^T+eb), a = tanh(v@aW^T+ab) ----------------
// grid = B*L blocks, 128 threads. Thread d computes e[d], a[d].
__global__ void kern_ea(const int* __restrict__ skills,
                        const int* __restrict__ responses,
                        const float* __restrict__ v_emb,
                        const float* __restrict__ e_W, const float* __restrict__ e_b,
                        const float* __restrict__ a_W, const float* __restrict__ a_b,
                        float* __restrict__ e_out, float* __restrict__ a_out) {
    int bl = blockIdx.x;
    int d  = threadIdx.x;
    __shared__ float vrow[Dd];
    int r  = responses[bl];
    int mr = (r > -1) ? r : 0;
    int x  = skills[bl] + NSs * mr;
    vrow[d] = v_emb[(size_t)x * Dd + d];
    __syncthreads();
    float acc_e = 0.f, acc_a = 0.f;
    const float* ew = e_W + d * Dd;
    const float* aw = a_W + d * Dd;
#pragma unroll 4
    for (int j = 0; j < Dd; ++j) {
        float v = vrow[j];
        acc_e = fmaf(v, ew[j], acc_e);
        acc_a = fmaf(v, aw[j], acc_a);
    }
    acc_e += e_b[d];
    acc_a += a_b[d];
    e_out[bl * Dd + d] = 1.f / (1.f + expf(-acc_e));
    a_out[bl * Dd + d] = tanhf(acc_a);
}

// ---------------- kernel 3: sequential memory scan ----------------
// Recurrence is independent per (b,d): thread (b,d) keeps all M=50 memory slots
// in registers. grid = B blocks, 128 threads (one per d).
__global__ void __launch_bounds__(128) kern_scan(
        const float* __restrict__ Mv0,
        const float* __restrict__ w_ws,
        const float* __restrict__ e_ws,
        const float* __restrict__ a_ws,
        float* __restrict__ read_ws) {
    int b = blockIdx.x;
    int d = threadIdx.x;
    float mv[Mm];
#pragma unroll
    for (int m = 0; m < Mm; ++m) mv[m] = Mv0[m * Dd + d];
    __shared__ float wbuf[Mm];
    for (int step = 0; step < Ll; ++step) {
        int bl = b * Ll + step;
        if (d < Mm) wbuf[d] = w_ws[bl * Mm + d];
        __syncthreads();
        float e_d = e_ws[bl * Dd + d];
        float a_d = a_ws[bl * Dd + d];
        float acc = 0.f;
#pragma unroll
        for (int m = 0; m < Mm; ++m) {
            float wm = wbuf[m];
            acc = fmaf(wm, mv[m], acc);              // read uses PRE-update value
            mv[m] = fmaf(wm, fmaf(-e_d, mv[m], a_d), mv[m]);  // mv += w*(a - e*mv)
        }
        read_ws[bl * Dd + d] = acc;
        __syncthreads();  // protect wbuf for next step's write
    }
}

// ---------------- kernel 4: head  p = sigmoid(tanh([read|k]@fW^T+fb)@pW^T+pb) ----------------
// grid = B*(L-1) blocks, 128 threads. Thread d computes f[d]; block reduces to p.
__global__ void kern_out(const int* __restrict__ skills,
                         const float* __restrict__ read_ws,
                         const float* __restrict__ k_emb,
                         const float* __restrict__ f_W, const float* __restrict__ f_b,
                         const float* __restrict__ p_W, const float* __restrict__ p_b,
                         float* __restrict__ out) {
    int idx = blockIdx.x;                 // b*(L-1) + (l-1)
    int b = idx / (Ll - 1);
    int l = idx % (Ll - 1) + 1;
    int d = threadIdx.x;
    __shared__ float crow[2 * Dd];
    int bl = b * Ll + l;
    crow[d]      = read_ws[bl * Dd + d];
    crow[Dd + d] = k_emb[skills[bl] * Dd + d];
    __syncthreads();
    const float* fw = f_W + d * 2 * Dd;
    float acc = 0.f;
#pragma unroll 4
    for (int j = 0; j < 2 * Dd; ++j) acc = fmaf(crow[j], fw[j], acc);
    float f  = tanhf(acc + f_b[d]);
    float pp = f * p_W[d];
    for (int off = 32; off > 0; off >>= 1) pp += __shfl_down(pp, off);
    __shared__ float pw2[2];
    if ((d & 63) == 0) pw2[d >> 6] = pp;
    __syncthreads();
    if (d == 0) {
        float s = pw2[0] + pw2[1] + p_b[0];
        out[idx] = 1.f / (1.f + expf(-s));
    }
}

extern "C" void kernel_launch(void* const* d_in, const int* in_sizes, int n_in,
                              void* d_out, int out_size, void* d_ws, size_t ws_size,
                              hipStream_t stream) {
    const int*   skills    = (const int*)  d_in[0];
    const int*   responses = (const int*)  d_in[1];
    const float* k_emb     = (const float*)d_in[2];
    const float* v_emb     = (const float*)d_in[3];
    const float* Mk        = (const float*)d_in[4];
    const float* Mv0       = (const float*)d_in[5];
    const float* e_W       = (const float*)d_in[6];
    const float* e_b       = (const float*)d_in[7];
    const float* a_W       = (const float*)d_in[8];
    const float* a_b       = (const float*)d_in[9];
    const float* f_W       = (const float*)d_in[10];
    const float* f_b       = (const float*)d_in[11];
    const float* p_W       = (const float*)d_in[12];
    const float* p_b       = (const float*)d_in[13];
    (void)in_sizes; (void)n_in; (void)out_size; (void)ws_size;

    float* out = (float*)d_out;

    float* ws      = (float*)d_ws;
    float* w_ws    = ws;                                  // B*L*M
    float* e_ws    = w_ws + (size_t)Bb * Ll * Mm;         // B*L*D
    float* a_ws    = e_ws + (size_t)Bb * Ll * Dd;         // B*L*D
    float* read_ws = a_ws + (size_t)Bb * Ll * Dd;         // B*L*D

    kern_w   <<<Bb * Ll,        64,  0, stream>>>(skills, k_emb, Mk, w_ws);
    kern_ea  <<<Bb * Ll,        128, 0, stream>>>(skills, responses, v_emb, e_W, e_b, a_W, a_b, e_ws, a_ws);
    kern_scan<<<Bb,             128, 0, stream>>>(Mv0, w_ws, e_ws, a_ws, read_ws);
    kern_out <<<Bb * (Ll - 1),  128, 0, stream>>>(skills, read_ws, k_emb, f_W, f_b, p_W, p_b, out);
}

// Round 3
// 376.791 us; speedup vs baseline: 2.1703x; 2.1703x over previous
//
#include <hip/hip_runtime.h>
#include <hip/hip_bf16.h>

#define Bb 64
#define Ll 200
#define NSs 1000
#define Dd 128
#define Mm 50

// ============ kernel 1: w = softmax(k @ Mk^T) over M=50 ============
// grid = B*L/4 blocks, 256 threads = 4 waves, one position per wave.
// Mk staged once per block into padded LDS (coalesced float4 loads).
__global__ void __launch_bounds__(256) kern_w(
        const int* __restrict__ skills,
        const float* __restrict__ k_emb,
        const float* __restrict__ Mk,
        float* __restrict__ w_out) {
    __shared__ float mk[Mm][Dd + 1];   // pad -> (m + j) % 32 banks, conflict-free
    __shared__ float kr[4][Dd];
    int tid = threadIdx.x;

    // stage Mk: 6400 floats = 1600 float4
    for (int lin = tid; lin < (Mm * Dd) / 4; lin += 256) {
        float4 f = ((const float4*)Mk)[lin];
        int m = lin >> 5;          // 32 float4 per row
        int j = (lin & 31) * 4;
        mk[m][j + 0] = f.x; mk[m][j + 1] = f.y; mk[m][j + 2] = f.z; mk[m][j + 3] = f.w;
    }
    int wave = tid >> 6;
    int lane = tid & 63;
    int bl   = blockIdx.x * 4 + wave;
    int sk   = skills[bl];
    kr[wave][lane]      = k_emb[sk * Dd + lane];
    kr[wave][64 + lane] = k_emb[sk * Dd + 64 + lane];
    __syncthreads();

    float logit = -1e30f;
    if (lane < Mm) {
        float acc = 0.f;
#pragma unroll 8
        for (int j = 0; j < Dd; ++j) acc = fmaf(kr[wave][j], mk[lane][j], acc);
        logit = acc;
    }
    float mx = logit;
    for (int off = 32; off > 0; off >>= 1) mx = fmaxf(mx, __shfl_down(mx, off));
    mx = __shfl(mx, 0);
    float ex = (lane < Mm) ? expf(logit - mx) : 0.f;
    float sm = ex;
    for (int off = 32; off > 0; off >>= 1) sm += __shfl_down(sm, off);
    sm = __shfl(sm, 0);
    if (lane < Mm) w_out[bl * Mm + lane] = ex / sm;
}

// ============ kernel 2: e = sigmoid(V@eW^T+eb), a = tanh(V@aW^T+ab) ============
// Tiled GEMM: 32 positions/block, 256 threads, d in 4 chunks of 32.
__global__ void __launch_bounds__(256) kern_ea(
        const int* __restrict__ skills,
        const int* __restrict__ responses,
        const float* __restrict__ v_emb,
        const float* __restrict__ e_W, const float* __restrict__ e_b,
        const float* __restrict__ a_W, const float* __restrict__ a_b,
        float* __restrict__ e_out, float* __restrict__ a_out) {
    __shared__ float vt[32][Dd + 1];
    __shared__ float we[32][Dd + 1];
    __shared__ float wa[32][Dd + 1];
    int tid = threadIdx.x;
    int blk = blockIdx.x;

    // stage 32 gathered v rows: 32 rows x 32 float4
    for (int q = 0; q < 4; ++q) {
        int lin = q * 256 + tid;          // 0..1023
        int r   = lin >> 5;
        int j4  = lin & 31;
        int bl  = blk * 32 + r;
        int rr  = responses[bl];
        int x   = skills[bl] + NSs * ((rr > -1) ? rr : 0);
        float4 f = ((const float4*)(v_emb + (size_t)x * Dd))[j4];
        int j = j4 * 4;
        vt[r][j + 0] = f.x; vt[r][j + 1] = f.y; vt[r][j + 2] = f.z; vt[r][j + 3] = f.w;
    }

    int d_loc = tid & 31;
    int pg    = tid >> 5;        // 0..7, 4 positions each
    for (int chunk = 0; chunk < 4; ++chunk) {
        int d0 = chunk * 32;
        __syncthreads();         // protect tiles from previous chunk's readers
        for (int q = 0; q < 4; ++q) {
            int lin = q * 256 + tid;      // float4 index into 32x128 tile
            int dr  = lin >> 5;
            int j4  = lin & 31;
            int j   = j4 * 4;
            float4 fe = ((const float4*)(e_W + (size_t)(d0 + dr) * Dd))[j4];
            we[dr][j + 0] = fe.x; we[dr][j + 1] = fe.y; we[dr][j + 2] = fe.z; we[dr][j + 3] = fe.w;
            float4 fa = ((const float4*)(a_W + (size_t)(d0 + dr) * Dd))[j4];
            wa[dr][j + 0] = fa.x; wa[dr][j + 1] = fa.y; wa[dr][j + 2] = fa.z; wa[dr][j + 3] = fa.w;
        }
        __syncthreads();

        float acc_e[4] = {0.f, 0.f, 0.f, 0.f};
        float acc_a[4] = {0.f, 0.f, 0.f, 0.f};
#pragma unroll 4
        for (int j = 0; j < Dd; ++j) {
            float fwe = we[d_loc][j];
            float fwa = wa[d_loc][j];
#pragma unroll
            for (int pp = 0; pp < 4; ++pp) {
                float v = vt[pg * 4 + pp][j];
                acc_e[pp] = fmaf(v, fwe, acc_e[pp]);
                acc_a[pp] = fmaf(v, fwa, acc_a[pp]);
            }
        }
        float eb = e_b[d0 + d_loc];
        float ab = a_b[d0 + d_loc];
#pragma unroll
        for (int pp = 0; pp < 4; ++pp) {
            int bl = blk * 32 + pg * 4 + pp;
            e_out[(size_t)bl * Dd + d0 + d_loc] = 1.f / (1.f + expf(-(acc_e[pp] + eb)));
            a_out[(size_t)bl * Dd + d0 + d_loc] = tanhf(acc_a[pp] + ab);
        }
    }
}

// ============ kernel 3: sequential memory scan ============
// grid = B blocks, 128 threads (one per d); M=50 state in registers.
// Next step's w/e/a prefetched (double-buffered wbuf + register e,a).
__global__ void __launch_bounds__(128) kern_scan(
        const float* __restrict__ Mv0,
        const float* __restrict__ w_ws,
        const float* __restrict__ e_ws,
        const float* __restrict__ a_ws,
        float* __restrict__ read_ws) {
    int b = blockIdx.x;
    int d = threadIdx.x;
    float mv[Mm];
#pragma unroll
    for (int m = 0; m < Mm; ++m) mv[m] = Mv0[m * Dd + d];

    __shared__ float wbuf[2][Mm];
    if (d < Mm) wbuf[0][d] = w_ws[(size_t)(b * Ll) * Mm + d];
    float e_d = e_ws[(size_t)(b * Ll) * Dd + d];
    float a_d = a_ws[(size_t)(b * Ll) * Dd + d];
    __syncthreads();

    for (int step = 0; step < Ll; ++step) {
        int cur = step & 1;
        float en = 0.f, an = 0.f;
        if (step + 1 < Ll) {                       // prefetch next step
            int bl1 = b * Ll + step + 1;
            if (d < Mm) wbuf[1 - cur][d] = w_ws[(size_t)bl1 * Mm + d];
            en = e_ws[(size_t)bl1 * Dd + d];
            an = a_ws[(size_t)bl1 * Dd + d];
        }
        float acc0 = 0.f, acc1 = 0.f;
#pragma unroll
        for (int m = 0; m < Mm; m += 2) {
            float w0 = wbuf[cur][m];
            float w1 = wbuf[cur][m + 1];
            acc0 = fmaf(w0, mv[m], acc0);
            mv[m] = fmaf(w0, fmaf(-e_d, mv[m], a_d), mv[m]);
            acc1 = fmaf(w1, mv[m + 1], acc1);
            mv[m + 1] = fmaf(w1, fmaf(-e_d, mv[m + 1], a_d), mv[m + 1]);
        }
        read_ws[(size_t)(b * Ll + step) * Dd + d] = acc0 + acc1;
        e_d = en; a_d = an;
        __syncthreads();                            // publish wbuf[1-cur]
    }
}

// ============ kernel 4: p = sigmoid(tanh([read|k]@fW^T+fb) @ pW^T + pb) ============
// 32 positions/block, 256 threads; f_W in 8 chunks of 16 rows.
__global__ void __launch_bounds__(256) kern_out(
        const int* __restrict__ skills,
        const float* __restrict__ read_ws,
        const float* __restrict__ k_emb,
        const float* __restrict__ f_W, const float* __restrict__ f_b,
        const float* __restrict__ p_W, const float* __restrict__ p_b,
        float* __restrict__ out) {
    __shared__ float ct[32][2 * Dd + 1];   // [read | k], pad
    __shared__ float wf[16][2 * Dd + 1];
    int tid = threadIdx.x;
    int blk = blockIdx.x;

    // stage 32 rows of [read|k]: per row 64 float4 (32 read + 32 k)
    for (int q = 0; q < 8; ++q) {
        int r   = q * 4 + (tid >> 6);
        int j4  = tid & 63;
        int idx = blk * 32 + r;             // b*(L-1) + (l-1)
        int b   = idx / (Ll - 1);
        int l   = idx % (Ll - 1) + 1;
        int bl  = b * Ll + l;
        float4 f;
        int j;
        if (j4 < 32) {
            f = ((const float4*)(read_ws + (size_t)bl * Dd))[j4];
            j = j4 * 4;
        } else {
            int sk = skills[bl];
            f = ((const float4*)(k_emb + (size_t)sk * Dd))[j4 - 32];
            j = Dd + (j4 - 32) * 4;
        }
        ct[r][j + 0] = f.x; ct[r][j + 1] = f.y; ct[r][j + 2] = f.z; ct[r][j + 3] = f.w;
    }

    int d_loc = tid & 15;
    int pg    = tid >> 4;          // 0..15, 2 positions each
    float ppart[2] = {0.f, 0.f};
    for (int chunk = 0; chunk < 8; ++chunk) {
        int d0 = chunk * 16;
        __syncthreads();
        // stage f_W rows d0..d0+15 (16 x 256 floats = 1024 float4)
        for (int q = 0; q < 4; ++q) {
            int lin = q * 256 + tid;
            int dr  = lin >> 6;            // 64 float4 per row
            int j4  = lin & 63;
            float4 f = ((const float4*)(f_W + (size_t)(d0 + dr) * 2 * Dd))[j4];
            int j = j4 * 4;
            wf[dr][j + 0] = f.x; wf[dr][j + 1] = f.y; wf[dr][j + 2] = f.z; wf[dr][j + 3] = f.w;
        }
        __syncthreads();

        float acc[2] = {0.f, 0.f};
#pragma unroll 4
        for (int j = 0; j < 2 * Dd; ++j) {
            float w = wf[d_loc][j];
            acc[0] = fmaf(ct[pg * 2 + 0][j], w, acc[0]);
            acc[1] = fmaf(ct[pg * 2 + 1][j], w, acc[1]);
        }
        float fb = f_b[d0 + d_loc];
        float pw = p_W[d0 + d_loc];
#pragma unroll
        for (int pp = 0; pp < 2; ++pp) {
            float f = tanhf(acc[pp] + fb);
            ppart[pp] = fmaf(f, pw, ppart[pp]);
        }
    }
    // reduce ppart over the 16 d_loc lanes of each pg (lanes are consecutive)
#pragma unroll
    for (int pp = 0; pp < 2; ++pp) {
        float v = ppart[pp];
        for (int off = 8; off > 0; off >>= 1) v += __shfl_down(v, off);
        ppart[pp] = v;
    }
    if (d_loc == 0) {
        float pb = p_b[0];
#pragma unroll
        for (int pp = 0; pp < 2; ++pp) {
            int idx = blk * 32 + pg * 2 + pp;
            out[idx] = 1.f / (1.f + expf(-(ppart[pp] + pb)));
        }
    }
}

extern "C" void kernel_launch(void* const* d_in, const int* in_sizes, int n_in,
                              void* d_out, int out_size, void* d_ws, size_t ws_size,
                              hipStream_t stream) {
    const int*   skills    = (const int*)  d_in[0];
    const int*   responses = (const int*)  d_in[1];
    const float* k_emb     = (const float*)d_in[2];
    const float* v_emb     = (const float*)d_in[3];
    const float* Mk        = (const float*)d_in[4];
    const float* Mv0       = (const float*)d_in[5];
    const float* e_W       = (const float*)d_in[6];
    const float* e_b       = (const float*)d_in[7];
    const float* a_W       = (const float*)d_in[8];
    const float* a_b       = (const float*)d_in[9];
    const float* f_W       = (const float*)d_in[10];
    const float* f_b       = (const float*)d_in[11];
    const float* p_W       = (const float*)d_in[12];
    const float* p_b       = (const float*)d_in[13];
    (void)in_sizes; (void)n_in; (void)out_size; (void)ws_size;

    float* out = (float*)d_out;

    float* ws      = (float*)d_ws;
    float* w_ws    = ws;                                  // B*L*M
    float* e_ws    = w_ws + (size_t)Bb * Ll * Mm;         // B*L*D
    float* a_ws    = e_ws + (size_t)Bb * Ll * Dd;         // B*L*D
    float* read_ws = a_ws + (size_t)Bb * Ll * Dd;         // B*L*D

    kern_w   <<<Bb * Ll / 4,            256, 0, stream>>>(skills, k_emb, Mk, w_ws);
    kern_ea  <<<Bb * Ll / 32,           256, 0, stream>>>(skills, responses, v_emb, e_W, e_b, a_W, a_b, e_ws, a_ws);
    kern_scan<<<Bb,                     128, 0, stream>>>(Mv0, w_ws, e_ws, a_ws, read_ws);
    kern_out <<<Bb * (Ll - 1) / 32,     256, 0, stream>>>(skills, read_ws, k_emb, f_W, f_b, p_W, p_b, out);
}

// Round 4
// 238.392 us; speedup vs baseline: 3.4303x; 1.5806x over previous
//
#include <hip/hip_runtime.h>
#include <hip/hip_bf16.h>

#define Bb 64
#define Ll 200
#define NSs 1000
#define Dd 128
#define Mm 50

__device__ __forceinline__ float bcast_lane(float v, int l) {
    return __int_as_float(__builtin_amdgcn_readlane(__float_as_int(v), l));
}

// ============ kernel 1: w = softmax(k @ Mk^T) over M=50 ============
__global__ void __launch_bounds__(256) kern_w(
        const int* __restrict__ skills,
        const float* __restrict__ k_emb,
        const float* __restrict__ Mk,
        float* __restrict__ w_out) {
    __shared__ float mk[Mm][Dd + 1];
    __shared__ float kr[4][Dd];
    int tid = threadIdx.x;

    for (int lin = tid; lin < (Mm * Dd) / 4; lin += 256) {
        float4 f = ((const float4*)Mk)[lin];
        int m = lin >> 5;
        int j = (lin & 31) * 4;
        mk[m][j + 0] = f.x; mk[m][j + 1] = f.y; mk[m][j + 2] = f.z; mk[m][j + 3] = f.w;
    }
    int wave = tid >> 6;
    int lane = tid & 63;
    int bl   = blockIdx.x * 4 + wave;
    int sk   = skills[bl];
    kr[wave][lane]      = k_emb[sk * Dd + lane];
    kr[wave][64 + lane] = k_emb[sk * Dd + 64 + lane];
    __syncthreads();

    float logit = -1e30f;
    if (lane < Mm) {
        float acc = 0.f;
#pragma unroll 8
        for (int j = 0; j < Dd; ++j) acc = fmaf(kr[wave][j], mk[lane][j], acc);
        logit = acc;
    }
    float mx = logit;
    for (int off = 32; off > 0; off >>= 1) mx = fmaxf(mx, __shfl_down(mx, off));
    mx = __shfl(mx, 0);
    float ex = (lane < Mm) ? expf(logit - mx) : 0.f;
    float sm = ex;
    for (int off = 32; off > 0; off >>= 1) sm += __shfl_down(sm, off);
    sm = __shfl(sm, 0);
    if (lane < Mm) w_out[bl * Mm + lane] = ex / sm;
}

// ============ kernel 2: e = sigmoid(V@eW^T+eb), a = tanh(V@aW^T+ab) ============
__global__ void __launch_bounds__(256) kern_ea(
        const int* __restrict__ skills,
        const int* __restrict__ responses,
        const float* __restrict__ v_emb,
        const float* __restrict__ e_W, const float* __restrict__ e_b,
        const float* __restrict__ a_W, const float* __restrict__ a_b,
        float* __restrict__ e_out, float* __restrict__ a_out) {
    __shared__ float vt[32][Dd + 1];
    __shared__ float we[32][Dd + 1];
    __shared__ float wa[32][Dd + 1];
    int tid = threadIdx.x;
    int blk = blockIdx.x;

    for (int q = 0; q < 4; ++q) {
        int lin = q * 256 + tid;
        int r   = lin >> 5;
        int j4  = lin & 31;
        int bl  = blk * 32 + r;
        int rr  = responses[bl];
        int x   = skills[bl] + NSs * ((rr > -1) ? rr : 0);
        float4 f = ((const float4*)(v_emb + (size_t)x * Dd))[j4];
        int j = j4 * 4;
        vt[r][j + 0] = f.x; vt[r][j + 1] = f.y; vt[r][j + 2] = f.z; vt[r][j + 3] = f.w;
    }

    int d_loc = tid & 31;
    int pg    = tid >> 5;
    for (int chunk = 0; chunk < 4; ++chunk) {
        int d0 = chunk * 32;
        __syncthreads();
        for (int q = 0; q < 4; ++q) {
            int lin = q * 256 + tid;
            int dr  = lin >> 5;
            int j4  = lin & 31;
            int j   = j4 * 4;
            float4 fe = ((const float4*)(e_W + (size_t)(d0 + dr) * Dd))[j4];
            we[dr][j + 0] = fe.x; we[dr][j + 1] = fe.y; we[dr][j + 2] = fe.z; we[dr][j + 3] = fe.w;
            float4 fa = ((const float4*)(a_W + (size_t)(d0 + dr) * Dd))[j4];
            wa[dr][j + 0] = fa.x; wa[dr][j + 1] = fa.y; wa[dr][j + 2] = fa.z; wa[dr][j + 3] = fa.w;
        }
        __syncthreads();

        float acc_e[4] = {0.f, 0.f, 0.f, 0.f};
        float acc_a[4] = {0.f, 0.f, 0.f, 0.f};
#pragma unroll 4
        for (int j = 0; j < Dd; ++j) {
            float fwe = we[d_loc][j];
            float fwa = wa[d_loc][j];
#pragma unroll
            for (int pp = 0; pp < 4; ++pp) {
                float v = vt[pg * 4 + pp][j];
                acc_e[pp] = fmaf(v, fwe, acc_e[pp]);
                acc_a[pp] = fmaf(v, fwa, acc_a[pp]);
            }
        }
        float eb = e_b[d0 + d_loc];
        float ab = a_b[d0 + d_loc];
#pragma unroll
        for (int pp = 0; pp < 4; ++pp) {
            int bl = blk * 32 + pg * 4 + pp;
            e_out[(size_t)bl * Dd + d0 + d_loc] = 1.f / (1.f + expf(-(acc_e[pp] + eb)));
            a_out[(size_t)bl * Dd + d0 + d_loc] = tanhf(acc_a[pp] + ab);
        }
    }
}

// ============ scan pass 1: per-chunk affine transfer (P, Q) ============
// mv_out = P * mv_in + Q over the chunk's T steps. Block = (b, c), 128 thr.
__global__ void __launch_bounds__(128) kern_scan_pq(
        const float* __restrict__ w_ws,
        const float* __restrict__ e_ws,
        const float* __restrict__ a_ws,
        float* __restrict__ P_ws, float* __restrict__ Q_ws,
        int C, int T) {
    int b = blockIdx.x / C, c = blockIdx.x % C;
    int d = threadIdx.x;
    int lane = d & 63;
    float P[Mm], Q[Mm];
#pragma unroll
    for (int m = 0; m < Mm; ++m) { P[m] = 1.f; Q[m] = 0.f; }

    size_t blBase = (size_t)b * Ll + (size_t)c * T;
    float wv  = (lane < Mm) ? w_ws[blBase * Mm + lane] : 0.f;
    float e_d = e_ws[blBase * Dd + d];
    float a_d = a_ws[blBase * Dd + d];

    for (int t = 0; t < T; ++t) {
        float wn = 0.f, en = 0.f, an = 0.f;
        if (t + 1 < T) {
            size_t bl1 = blBase + t + 1;
            wn = (lane < Mm) ? w_ws[bl1 * Mm + lane] : 0.f;
            en = e_ws[bl1 * Dd + d];
            an = a_ws[bl1 * Dd + d];
        }
#pragma unroll
        for (int m = 0; m < Mm; ++m) {
            float wm = bcast_lane(wv, m);
            float A  = fmaf(-wm, e_d, 1.f);
            Q[m] = fmaf(A, Q[m], wm * a_d);
            P[m] *= A;
        }
        wv = wn; e_d = en; a_d = an;
    }
    size_t base = ((size_t)(b * C + c)) * (Mm * Dd) + d;
#pragma unroll
    for (int m = 0; m < Mm; ++m) {
        P_ws[base + m * Dd] = P[m];
        Q_ws[base + m * Dd] = Q[m];
    }
}

// ============ scan pass 2: sequential chunk-boundary combine ============
// S[b][c-1] = start state of chunk c (c = 1..C-1). Thread per (b,m,d).
__global__ void kern_scan_comb(
        const float* __restrict__ Mv0,
        const float* __restrict__ P_ws, const float* __restrict__ Q_ws,
        float* __restrict__ S_ws, int C) {
    int idx = blockIdx.x * 256 + threadIdx.x;     // 0 .. B*M*D-1
    int b   = idx / (Mm * Dd);
    int md  = idx % (Mm * Dd);
    float s = Mv0[md];
    for (int c = 0; c < C - 1; ++c) {
        size_t pq = ((size_t)(b * C + c)) * (Mm * Dd) + md;
        s = fmaf(P_ws[pq], s, Q_ws[pq]);
        S_ws[((size_t)(b * (C - 1) + c)) * (Mm * Dd) + md] = s;
    }
}

// ============ scan pass 3: rescan chunk from known start, emit read ============
__global__ void __launch_bounds__(128) kern_scan_rd(
        const float* __restrict__ Mv0,
        const float* __restrict__ S_ws,
        const float* __restrict__ w_ws,
        const float* __restrict__ e_ws,
        const float* __restrict__ a_ws,
        float* __restrict__ read_ws,
        int C, int T) {
    int b = blockIdx.x / C, c = blockIdx.x % C;
    int d = threadIdx.x;
    int lane = d & 63;
    float mv[Mm];
    if (c == 0) {
#pragma unroll
        for (int m = 0; m < Mm; ++m) mv[m] = Mv0[m * Dd + d];
    } else {
        size_t sb = ((size_t)(b * (C - 1) + (c - 1))) * (Mm * Dd) + d;
#pragma unroll
        for (int m = 0; m < Mm; ++m) mv[m] = S_ws[sb + m * Dd];
    }

    size_t blBase = (size_t)b * Ll + (size_t)c * T;
    float wv  = (lane < Mm) ? w_ws[blBase * Mm + lane] : 0.f;
    float e_d = e_ws[blBase * Dd + d];
    float a_d = a_ws[blBase * Dd + d];

    for (int t = 0; t < T; ++t) {
        float wn = 0.f, en = 0.f, an = 0.f;
        if (t + 1 < T) {
            size_t bl1 = blBase + t + 1;
            wn = (lane < Mm) ? w_ws[bl1 * Mm + lane] : 0.f;
            en = e_ws[bl1 * Dd + d];
            an = a_ws[bl1 * Dd + d];
        }
        float acc0 = 0.f, acc1 = 0.f, acc2 = 0.f, acc3 = 0.f;
#pragma unroll
        for (int m = 0; m < Mm; m += 4) {
            float w0 = bcast_lane(wv, m);
            float w1 = bcast_lane(wv, m + 1);
            float w2 = (m + 2 < Mm) ? bcast_lane(wv, m + 2) : 0.f;
            float w3 = (m + 3 < Mm) ? bcast_lane(wv, m + 3) : 0.f;
            acc0 = fmaf(w0, mv[m], acc0);
            mv[m] = fmaf(w0, fmaf(-e_d, mv[m], a_d), mv[m]);
            acc1 = fmaf(w1, mv[m + 1], acc1);
            mv[m + 1] = fmaf(w1, fmaf(-e_d, mv[m + 1], a_d), mv[m + 1]);
            if (m + 2 < Mm) {
                acc2 = fmaf(w2, mv[m + 2], acc2);
                mv[m + 2] = fmaf(w2, fmaf(-e_d, mv[m + 2], a_d), mv[m + 2]);
                acc3 = fmaf(w3, mv[m + 3], acc3);
                mv[m + 3] = fmaf(w3, fmaf(-e_d, mv[m + 3], a_d), mv[m + 3]);
            }
        }
        read_ws[(blBase + t) * Dd + d] = (acc0 + acc1) + (acc2 + acc3);
        wv = wn; e_d = en; a_d = an;
    }
}

// ============ kernel 4: p = sigmoid(tanh([read|k]@fW^T+fb) @ pW^T + pb) ============
__global__ void __launch_bounds__(256) kern_out(
        const int* __restrict__ skills,
        const float* __restrict__ read_ws,
        const float* __restrict__ k_emb,
        const float* __restrict__ f_W, const float* __restrict__ f_b,
        const float* __restrict__ p_W, const float* __restrict__ p_b,
        float* __restrict__ out) {
    __shared__ float ct[32][2 * Dd + 1];
    __shared__ float wf[16][2 * Dd + 1];
    int tid = threadIdx.x;
    int blk = blockIdx.x;

    for (int q = 0; q < 8; ++q) {
        int r   = q * 4 + (tid >> 6);
        int j4  = tid & 63;
        int idx = blk * 32 + r;
        int b   = idx / (Ll - 1);
        int l   = idx % (Ll - 1) + 1;
        int bl  = b * Ll + l;
        float4 f;
        int j;
        if (j4 < 32) {
            f = ((const float4*)(read_ws + (size_t)bl * Dd))[j4];
            j = j4 * 4;
        } else {
            int sk = skills[bl];
            f = ((const float4*)(k_emb + (size_t)sk * Dd))[j4 - 32];
            j = Dd + (j4 - 32) * 4;
        }
        ct[r][j + 0] = f.x; ct[r][j + 1] = f.y; ct[r][j + 2] = f.z; ct[r][j + 3] = f.w;
    }

    int d_loc = tid & 15;
    int pg    = tid >> 4;
    float ppart[2] = {0.f, 0.f};
    for (int chunk = 0; chunk < 8; ++chunk) {
        int d0 = chunk * 16;
        __syncthreads();
        for (int q = 0; q < 4; ++q) {
            int lin = q * 256 + tid;
            int dr  = lin >> 6;
            int j4  = lin & 63;
            float4 f = ((const float4*)(f_W + (size_t)(d0 + dr) * 2 * Dd))[j4];
            int j = j4 * 4;
            wf[dr][j + 0] = f.x; wf[dr][j + 1] = f.y; wf[dr][j + 2] = f.z; wf[dr][j + 3] = f.w;
        }
        __syncthreads();

        float acc[2] = {0.f, 0.f};
#pragma unroll 4
        for (int j = 0; j < 2 * Dd; ++j) {
            float w = wf[d_loc][j];
            acc[0] = fmaf(ct[pg * 2 + 0][j], w, acc[0]);
            acc[1] = fmaf(ct[pg * 2 + 1][j], w, acc[1]);
        }
        float fb = f_b[d0 + d_loc];
        float pw = p_W[d0 + d_loc];
#pragma unroll
        for (int pp = 0; pp < 2; ++pp) {
            float f = tanhf(acc[pp] + fb);
            ppart[pp] = fmaf(f, pw, ppart[pp]);
        }
    }
#pragma unroll
    for (int pp = 0; pp < 2; ++pp) {
        float v = ppart[pp];
        for (int off = 8; off > 0; off >>= 1) v += __shfl_down(v, off);
        ppart[pp] = v;
    }
    if (d_loc == 0) {
        float pb = p_b[0];
#pragma unroll
        for (int pp = 0; pp < 2; ++pp) {
            int idx = blk * 32 + pg * 2 + pp;
            out[idx] = 1.f / (1.f + expf(-(ppart[pp] + pb)));
        }
    }
}

extern "C" void kernel_launch(void* const* d_in, const int* in_sizes, int n_in,
                              void* d_out, int out_size, void* d_ws, size_t ws_size,
                              hipStream_t stream) {
    const int*   skills    = (const int*)  d_in[0];
    const int*   responses = (const int*)  d_in[1];
    const float* k_emb     = (const float*)d_in[2];
    const float* v_emb     = (const float*)d_in[3];
    const float* Mk        = (const float*)d_in[4];
    const float* Mv0       = (const float*)d_in[5];
    const float* e_W       = (const float*)d_in[6];
    const float* e_b       = (const float*)d_in[7];
    const float* a_W       = (const float*)d_in[8];
    const float* a_b       = (const float*)d_in[9];
    const float* f_W       = (const float*)d_in[10];
    const float* f_b       = (const float*)d_in[11];
    const float* p_W       = (const float*)d_in[12];
    const float* p_b       = (const float*)d_in[13];
    (void)in_sizes; (void)n_in; (void)out_size;

    float* out = (float*)d_out;

    float* ws      = (float*)d_ws;
    float* w_ws    = ws;                                  // B*L*M
    float* e_ws    = w_ws + (size_t)Bb * Ll * Mm;         // B*L*D
    float* a_ws    = e_ws + (size_t)Bb * Ll * Dd;         // B*L*D
    float* read_ws = a_ws + (size_t)Bb * Ll * Dd;         // B*L*D
    float* extra   = read_ws + (size_t)Bb * Ll * Dd;

    // pick largest chunk count whose P/Q/S scratch fits in ws
    const size_t baseF = (size_t)Bb * Ll * Mm + 3 * (size_t)Bb * Ll * Dd;
    const size_t BMD   = (size_t)Bb * Mm * Dd;
    int C = 1;
    const int cands[3] = {8, 5, 2};
    for (int i = 0; i < 3; ++i) {
        size_t need = (baseF + BMD * (3 * (size_t)cands[i] - 1)) * sizeof(float);
        if (ws_size >= need) { C = cands[i]; break; }
    }
    int T = Ll / C;
    float* P_ws = extra;                                  // B*C*M*D
    float* Q_ws = P_ws + BMD * C;                         // B*C*M*D
    float* S_ws = Q_ws + BMD * C;                         // B*(C-1)*M*D

    kern_w   <<<Bb * Ll / 4,        256, 0, stream>>>(skills, k_emb, Mk, w_ws);
    kern_ea  <<<Bb * Ll / 32,       256, 0, stream>>>(skills, responses, v_emb, e_W, e_b, a_W, a_b, e_ws, a_ws);
    if (C > 1) {
        kern_scan_pq  <<<Bb * C, 128, 0, stream>>>(w_ws, e_ws, a_ws, P_ws, Q_ws, C, T);
        kern_scan_comb<<<(int)(BMD / 256), 256, 0, stream>>>(Mv0, P_ws, Q_ws, S_ws, C);
    }
    kern_scan_rd <<<Bb * C, 128, 0, stream>>>(Mv0, S_ws, w_ws, e_ws, a_ws, read_ws, C, T);
    kern_out <<<Bb * (Ll - 1) / 32, 256, 0, stream>>>(skills, read_ws, k_emb, f_W, f_b, p_W, p_b, out);
}

// Round 5
// 211.197 us; speedup vs baseline: 3.8720x; 1.1288x over previous
//
#include <hip/hip_runtime.h>
#include <hip/hip_bf16.h>

#define Bb 64
#define Ll 200
#define NSs 1000
#define Dd 128
#define Mm 50

__device__ __forceinline__ float bcast_lane(float v, int l) {
    return __int_as_float(__builtin_amdgcn_readlane(__float_as_int(v), l));
}

// ============ kernel 1: w = softmax(k @ Mk^T) over M=50 ============
// 16 pos/block (4 waves x 4 pos), Mk staged once, float4 LDS reads.
__global__ void __launch_bounds__(256) kern_w(
        const int* __restrict__ skills,
        const float* __restrict__ k_emb,
        const float* __restrict__ Mk,
        float* __restrict__ w_out) {
    __shared__ float mk[Mm][Dd + 4];
    __shared__ float kr[16][Dd + 4];
    int tid = threadIdx.x;
    int blk = blockIdx.x;

    for (int lin = tid; lin < (Mm * Dd) / 4; lin += 256) {   // 1600 float4
        float4 f = ((const float4*)Mk)[lin];
        int m = lin >> 5;
        int c4 = lin & 31;
        *(float4*)&mk[m][c4 * 4] = f;
    }
    for (int lin = tid; lin < 16 * 32; lin += 256) {          // 512 float4
        int r  = lin >> 5;
        int c4 = lin & 31;
        int bl = blk * 16 + r;
        float4 f = ((const float4*)(k_emb + (size_t)skills[bl] * Dd))[c4];
        *(float4*)&kr[r][c4 * 4] = f;
    }
    __syncthreads();

    int wave = tid >> 6;
    int lane = tid & 63;
    int mm   = (lane < Mm) ? lane : 0;
    float acc[4] = {0.f, 0.f, 0.f, 0.f};
#pragma unroll 2
    for (int q = 0; q < 32; ++q) {
        float4 mkv = *(const float4*)&mk[mm][q * 4];
#pragma unroll
        for (int i = 0; i < 4; ++i) {
            float4 kv = *(const float4*)&kr[wave * 4 + i][q * 4];
            acc[i] = fmaf(mkv.x, kv.x, acc[i]);
            acc[i] = fmaf(mkv.y, kv.y, acc[i]);
            acc[i] = fmaf(mkv.z, kv.z, acc[i]);
            acc[i] = fmaf(mkv.w, kv.w, acc[i]);
        }
    }
#pragma unroll
    for (int i = 0; i < 4; ++i) {
        float logit = (lane < Mm) ? acc[i] : -1e30f;
        float mx = logit;
        for (int off = 32; off > 0; off >>= 1) mx = fmaxf(mx, __shfl_down(mx, off));
        mx = __shfl(mx, 0);
        float ex = (lane < Mm) ? expf(logit - mx) : 0.f;
        float sm = ex;
        for (int off = 32; off > 0; off >>= 1) sm += __shfl_down(sm, off);
        sm = __shfl(sm, 0);
        int bl = blk * 16 + wave * 4 + i;
        if (lane < Mm) w_out[(size_t)bl * Mm + lane] = ex / sm;
    }
}

// ============ kernel 2: e = sigmoid(V@eW^T+eb), a = tanh(V@aW^T+ab) ============
// 32 pos/block, 256 thr = 4 waves. Wave w owns concat-out rows [w*64, w*64+64)
// in 2 chunks of 32 (wave-private LDS tile). Lane: 4 pos x 4 outs register tile.
__global__ void __launch_bounds__(256) kern_ea(
        const int* __restrict__ skills,
        const int* __restrict__ responses,
        const float* __restrict__ v_emb,
        const float* __restrict__ e_W, const float* __restrict__ e_b,
        const float* __restrict__ a_W, const float* __restrict__ a_b,
        float* __restrict__ e_out, float* __restrict__ a_out) {
    __shared__ float vt[32][Dd + 4];           // 16.9 KB
    __shared__ float wt[4][32][Dd + 4];        // 67.6 KB (wave-private slices)
    int tid = threadIdx.x;
    int blk = blockIdx.x;

    // stage 32 gathered v rows (1024 float4, coalesced, conflict-free b128 writes)
#pragma unroll
    for (int i = 0; i < 4; ++i) {
        int lin = i * 256 + tid;
        int r   = lin >> 5;
        int c4  = lin & 31;
        int bl  = blk * 32 + r;
        int rr  = responses[bl];
        int x   = skills[bl] + NSs * ((rr > -1) ? rr : 0);
        float4 f = ((const float4*)(v_emb + (size_t)x * Dd))[c4];
        *(float4*)&vt[r][c4 * 4] = f;
    }
    __syncthreads();

    int wave = tid >> 6, lane = tid & 63;
    int pg = lane >> 3, og = lane & 7;
    int p0 = pg * 4, o0 = og * 4;

    for (int s = 0; s < 2; ++s) {
        int base_row = wave * 64 + s * 32;               // concat space [0,256)
        bool is_e    = base_row < 128;
        const float* W = is_e ? e_W : a_W;
        int wrow0 = is_e ? base_row : base_row - 128;

        // wave stages its 32 weight rows (1024 float4 by 64 lanes)
#pragma unroll
        for (int i = 0; i < 16; ++i) {
            int lin = i * 64 + lane;
            int r   = lin >> 5;
            int c4  = lin & 31;
            float4 f = ((const float4*)(W + (size_t)(wrow0 + r) * Dd))[c4];
            *(float4*)&wt[wave][r][c4 * 4] = f;
        }
        __syncthreads();

        float acc[4][4] = {};
#pragma unroll 2
        for (int q = 0; q < 32; ++q) {
            float4 av[4], bv[4];
#pragma unroll
            for (int i = 0; i < 4; ++i) av[i] = *(const float4*)&vt[p0 + i][q * 4];
#pragma unroll
            for (int j = 0; j < 4; ++j) bv[j] = *(const float4*)&wt[wave][o0 + j][q * 4];
#pragma unroll
            for (int i = 0; i < 4; ++i)
#pragma unroll
                for (int j = 0; j < 4; ++j) {
                    acc[i][j] = fmaf(av[i].x, bv[j].x, acc[i][j]);
                    acc[i][j] = fmaf(av[i].y, bv[j].y, acc[i][j]);
                    acc[i][j] = fmaf(av[i].z, bv[j].z, acc[i][j]);
                    acc[i][j] = fmaf(av[i].w, bv[j].w, acc[i][j]);
                }
        }

        int rowm0 = wrow0 + o0;                 // row within the 128-wide output
        float4 bias = *(const float4*)((is_e ? e_b : a_b) + rowm0);
        float* dst  = is_e ? e_out : a_out;
#pragma unroll
        for (int i = 0; i < 4; ++i) {
            int bl = blk * 32 + p0 + i;
            float4 r;
            if (is_e) {
                r.x = 1.f / (1.f + expf(-(acc[i][0] + bias.x)));
                r.y = 1.f / (1.f + expf(-(acc[i][1] + bias.y)));
                r.z = 1.f / (1.f + expf(-(acc[i][2] + bias.z)));
                r.w = 1.f / (1.f + expf(-(acc[i][3] + bias.w)));
            } else {
                r.x = tanhf(acc[i][0] + bias.x);
                r.y = tanhf(acc[i][1] + bias.y);
                r.z = tanhf(acc[i][2] + bias.z);
                r.w = tanhf(acc[i][3] + bias.w);
            }
            *(float4*)&dst[(size_t)bl * Dd + rowm0] = r;
        }
        __syncthreads();   // wt[wave] restage safety for s=1
    }
}

// ============ scan pass 1: per-chunk affine transfer (P, Q) ============
__global__ void __launch_bounds__(128) kern_scan_pq(
        const float* __restrict__ w_ws,
        const float* __restrict__ e_ws,
        const float* __restrict__ a_ws,
        float* __restrict__ P_ws, float* __restrict__ Q_ws,
        int C, int T) {
    int b = blockIdx.x / C, c = blockIdx.x % C;
    int d = threadIdx.x;
    int lane = d & 63;
    float P[Mm], Q[Mm];
#pragma unroll
    for (int m = 0; m < Mm; ++m) { P[m] = 1.f; Q[m] = 0.f; }

    size_t blBase = (size_t)b * Ll + (size_t)c * T;
    float wv  = (lane < Mm) ? w_ws[blBase * Mm + lane] : 0.f;
    float e_d = e_ws[blBase * Dd + d];
    float a_d = a_ws[blBase * Dd + d];

    for (int t = 0; t < T; ++t) {
        float wn = 0.f, en = 0.f, an = 0.f;
        if (t + 1 < T) {
            size_t bl1 = blBase + t + 1;
            wn = (lane < Mm) ? w_ws[bl1 * Mm + lane] : 0.f;
            en = e_ws[bl1 * Dd + d];
            an = a_ws[bl1 * Dd + d];
        }
#pragma unroll
        for (int m = 0; m < Mm; ++m) {
            float wm = bcast_lane(wv, m);
            float A  = fmaf(-wm, e_d, 1.f);
            Q[m] = fmaf(A, Q[m], wm * a_d);
            P[m] *= A;
        }
        wv = wn; e_d = en; a_d = an;
    }
    size_t base = ((size_t)(b * C + c)) * (Mm * Dd) + d;
#pragma unroll
    for (int m = 0; m < Mm; ++m) {
        P_ws[base + m * Dd] = P[m];
        Q_ws[base + m * Dd] = Q[m];
    }
}

// ============ scan pass 2: sequential chunk-boundary combine ============
__global__ void kern_scan_comb(
        const float* __restrict__ Mv0,
        const float* __restrict__ P_ws, const float* __restrict__ Q_ws,
        float* __restrict__ S_ws, int C) {
    int idx = blockIdx.x * 256 + threadIdx.x;
    int b   = idx / (Mm * Dd);
    int md  = idx % (Mm * Dd);
    float s = Mv0[md];
    for (int c = 0; c < C - 1; ++c) {
        size_t pq = ((size_t)(b * C + c)) * (Mm * Dd) + md;
        s = fmaf(P_ws[pq], s, Q_ws[pq]);
        S_ws[((size_t)(b * (C - 1) + c)) * (Mm * Dd) + md] = s;
    }
}

// ============ scan pass 3: rescan chunk from known start, emit read ============
__global__ void __launch_bounds__(128) kern_scan_rd(
        const float* __restrict__ Mv0,
        const float* __restrict__ S_ws,
        const float* __restrict__ w_ws,
        const float* __restrict__ e_ws,
        const float* __restrict__ a_ws,
        float* __restrict__ read_ws,
        int C, int T) {
    int b = blockIdx.x / C, c = blockIdx.x % C;
    int d = threadIdx.x;
    int lane = d & 63;
    float mv[Mm];
    if (c == 0) {
#pragma unroll
        for (int m = 0; m < Mm; ++m) mv[m] = Mv0[m * Dd + d];
    } else {
        size_t sb = ((size_t)(b * (C - 1) + (c - 1))) * (Mm * Dd) + d;
#pragma unroll
        for (int m = 0; m < Mm; ++m) mv[m] = S_ws[sb + m * Dd];
    }

    size_t blBase = (size_t)b * Ll + (size_t)c * T;
    float wv  = (lane < Mm) ? w_ws[blBase * Mm + lane] : 0.f;
    float e_d = e_ws[blBase * Dd + d];
    float a_d = a_ws[blBase * Dd + d];

    for (int t = 0; t < T; ++t) {
        float wn = 0.f, en = 0.f, an = 0.f;
        if (t + 1 < T) {
            size_t bl1 = blBase + t + 1;
            wn = (lane < Mm) ? w_ws[bl1 * Mm + lane] : 0.f;
            en = e_ws[bl1 * Dd + d];
            an = a_ws[bl1 * Dd + d];
        }
        float acc0 = 0.f, acc1 = 0.f, acc2 = 0.f, acc3 = 0.f;
#pragma unroll
        for (int m = 0; m < Mm; m += 4) {
            float w0 = bcast_lane(wv, m);
            float w1 = bcast_lane(wv, m + 1);
            float w2 = (m + 2 < Mm) ? bcast_lane(wv, m + 2) : 0.f;
            float w3 = (m + 3 < Mm) ? bcast_lane(wv, m + 3) : 0.f;
            acc0 = fmaf(w0, mv[m], acc0);
            mv[m] = fmaf(w0, fmaf(-e_d, mv[m], a_d), mv[m]);
            acc1 = fmaf(w1, mv[m + 1], acc1);
            mv[m + 1] = fmaf(w1, fmaf(-e_d, mv[m + 1], a_d), mv[m + 1]);
            if (m + 2 < Mm) {
                acc2 = fmaf(w2, mv[m + 2], acc2);
                mv[m + 2] = fmaf(w2, fmaf(-e_d, mv[m + 2], a_d), mv[m + 2]);
                acc3 = fmaf(w3, mv[m + 3], acc3);
                mv[m + 3] = fmaf(w3, fmaf(-e_d, mv[m + 3], a_d), mv[m + 3]);
            }
        }
        read_ws[(blBase + t) * Dd + d] = (acc0 + acc1) + (acc2 + acc3);
        wv = wn; e_d = en; a_d = an;
    }
}

// ============ kernel 4: p = sigmoid(tanh([read|k]@fW^T+fb) @ pW^T + pb) ============
// 32 pos/block, 256 thr = 4 waves. Wave w owns f_W rows [w*32, w*32+32);
// K=256 staged in 2 halves (wave-private tile). Lane: 4 pos x 4 outs.
__global__ void __launch_bounds__(256) kern_out(
        const int* __restrict__ skills,
        const float* __restrict__ read_ws,
        const float* __restrict__ k_emb,
        const float* __restrict__ f_W, const float* __restrict__ f_b,
        const float* __restrict__ p_W, const float* __restrict__ p_b,
        float* __restrict__ out) {
    __shared__ float ct[32][2 * Dd + 8];        // 33.8 KB
    __shared__ float wt[4][32][Dd + 4];         // 67.6 KB
    __shared__ float pf[32][8];                 // per-wave partials
    int tid = threadIdx.x;
    int blk = blockIdx.x;

    // stage 32 rows of [read|k]: 2048 float4
#pragma unroll
    for (int i = 0; i < 8; ++i) {
        int lin = i * 256 + tid;
        int r   = lin >> 6;
        int c4  = lin & 63;
        int idx = blk * 32 + r;
        int b   = idx / (Ll - 1);
        int l   = idx % (Ll - 1) + 1;
        int bl  = b * Ll + l;
        float4 f;
        if (c4 < 32) f = ((const float4*)(read_ws + (size_t)bl * Dd))[c4];
        else         f = ((const float4*)(k_emb + (size_t)skills[bl] * Dd))[c4 - 32];
        *(float4*)&ct[r][c4 * 4] = f;
    }
    ((float*)pf)[tid] = 0.f;
    __syncthreads();

    int wave = tid >> 6, lane = tid & 63;
    int pg = lane >> 3, og = lane & 7;
    int p0 = pg * 4, o0 = og * 4;

    float acc[4][4] = {};
    for (int h = 0; h < 2; ++h) {
        // wave stages its 32 f_W rows, K columns [h*128, h*128+128)
#pragma unroll
        for (int i = 0; i < 16; ++i) {
            int lin = i * 64 + lane;
            int r   = lin >> 5;
            int c4  = lin & 31;
            float4 f = ((const float4*)(f_W + (size_t)(wave * 32 + r) * (2 * Dd)))[h * 32 + c4];
            *(float4*)&wt[wave][r][c4 * 4] = f;
        }
        __syncthreads();
#pragma unroll 2
        for (int q = 0; q < 32; ++q) {
            int k = h * 128 + q * 4;
            float4 av[4], bv[4];
#pragma unroll
            for (int i = 0; i < 4; ++i) av[i] = *(const float4*)&ct[p0 + i][k];
#pragma unroll
            for (int j = 0; j < 4; ++j) bv[j] = *(const float4*)&wt[wave][o0 + j][q * 4];
#pragma unroll
            for (int i = 0; i < 4; ++i)
#pragma unroll
                for (int j = 0; j < 4; ++j) {
                    acc[i][j] = fmaf(av[i].x, bv[j].x, acc[i][j]);
                    acc[i][j] = fmaf(av[i].y, bv[j].y, acc[i][j]);
                    acc[i][j] = fmaf(av[i].z, bv[j].z, acc[i][j]);
                    acc[i][j] = fmaf(av[i].w, bv[j].w, acc[i][j]);
                }
        }
        __syncthreads();
    }

    int row0 = wave * 32 + o0;
    float4 fb = *(const float4*)&f_b[row0];
    float4 pw = *(const float4*)&p_W[row0];
#pragma unroll
    for (int i = 0; i < 4; ++i) {
        float pp = 0.f;
        pp = fmaf(tanhf(acc[i][0] + fb.x), pw.x, pp);
        pp = fmaf(tanhf(acc[i][1] + fb.y), pw.y, pp);
        pp = fmaf(tanhf(acc[i][2] + fb.z), pw.z, pp);
        pp = fmaf(tanhf(acc[i][3] + fb.w), pw.w, pp);
        for (int off = 4; off > 0; off >>= 1) pp += __shfl_down(pp, off, 8);
        if (og == 0) pf[p0 + i][wave] = pp;
    }
    __syncthreads();
    if (tid < 32) {
        float s = pf[tid][0] + pf[tid][1] + pf[tid][2] + pf[tid][3] + p_b[0];
        out[blk * 32 + tid] = 1.f / (1.f + expf(-s));
    }
}

extern "C" void kernel_launch(void* const* d_in, const int* in_sizes, int n_in,
                              void* d_out, int out_size, void* d_ws, size_t ws_size,
                              hipStream_t stream) {
    const int*   skills    = (const int*)  d_in[0];
    const int*   responses = (const int*)  d_in[1];
    const float* k_emb     = (const float*)d_in[2];
    const float* v_emb     = (const float*)d_in[3];
    const float* Mk        = (const float*)d_in[4];
    const float* Mv0       = (const float*)d_in[5];
    const float* e_W       = (const float*)d_in[6];
    const float* e_b       = (const float*)d_in[7];
    const float* a_W       = (const float*)d_in[8];
    const float* a_b       = (const float*)d_in[9];
    const float* f_W       = (const float*)d_in[10];
    const float* f_b       = (const float*)d_in[11];
    const float* p_W       = (const float*)d_in[12];
    const float* p_b       = (const float*)d_in[13];
    (void)in_sizes; (void)n_in; (void)out_size;

    float* out = (float*)d_out;

    float* ws      = (float*)d_ws;
    float* w_ws    = ws;                                  // B*L*M
    float* e_ws    = w_ws + (size_t)Bb * Ll * Mm;         // B*L*D
    float* a_ws    = e_ws + (size_t)Bb * Ll * Dd;         // B*L*D
    float* read_ws = a_ws + (size_t)Bb * Ll * Dd;         // B*L*D
    float* extra   = read_ws + (size_t)Bb * Ll * Dd;

    const size_t baseF = (size_t)Bb * Ll * Mm + 3 * (size_t)Bb * Ll * Dd;
    const size_t BMD   = (size_t)Bb * Mm * Dd;
    int C = 1;
    const int cands[3] = {8, 5, 2};
    for (int i = 0; i < 3; ++i) {
        size_t need = (baseF + BMD * (3 * (size_t)cands[i] - 1)) * sizeof(float);
        if (ws_size >= need) { C = cands[i]; break; }
    }
    int T = Ll / C;
    float* P_ws = extra;
    float* Q_ws = P_ws + BMD * C;
    float* S_ws = Q_ws + BMD * C;

    kern_w   <<<Bb * Ll / 16,       256, 0, stream>>>(skills, k_emb, Mk, w_ws);
    kern_ea  <<<Bb * Ll / 32,       256, 0, stream>>>(skills, responses, v_emb, e_W, e_b, a_W, a_b, e_ws, a_ws);
    if (C > 1) {
        kern_scan_pq  <<<Bb * C, 128, 0, stream>>>(w_ws, e_ws, a_ws, P_ws, Q_ws, C, T);
        kern_scan_comb<<<(int)(BMD / 256), 256, 0, stream>>>(Mv0, P_ws, Q_ws, S_ws, C);
    }
    kern_scan_rd <<<Bb * C, 128, 0, stream>>>(Mv0, S_ws, w_ws, e_ws, a_ws, read_ws, C, T);
    kern_out <<<Bb * (Ll - 1) / 32, 256, 0, stream>>>(skills, read_ws, k_emb, f_W, f_b, p_W, p_b, out);
}